// Round 6
// baseline (1048.888 us; speedup 1.0000x reference)
//
#include <hip/hip_runtime.h>

#define NEG_SLOPE 0.2f
#define EPS_ 1e-9f

typedef __attribute__((ext_vector_type(8))) short short8v;
typedef __attribute__((ext_vector_type(4))) float f32x4;

__device__ __forceinline__ float bf2f(unsigned short u) {
    return __uint_as_float(((unsigned)u) << 16);
}
__device__ __forceinline__ unsigned short f2bf(float f) {
    unsigned u = __float_as_uint(f);
    u = u + 0x7FFFu + ((u >> 16) & 1u);   // round-to-nearest-even
    return (unsigned short)(u >> 16);
}

// ------------------- CSR build (node edge-lists PADDED to even length) ---------
__global__ void hist_kernel(const int* __restrict__ src, int* __restrict__ cnt, int E) {
    int i = blockIdx.x * blockDim.x + threadIdx.x;
    if (i < E) atomicAdd(&cnt[src[i]], 1);
}

__global__ __launch_bounds__(256) void scan1_kernel(const int* __restrict__ cnt,
        int* __restrict__ locpre, int* __restrict__ blocksum, int n) {
    int t = threadIdx.x;
    int lane = t & 63, wid = t >> 6;
    int base = blockIdx.x * 1024 + t * 4;
    int4 v = {0, 0, 0, 0};
    if (base + 3 < n) {
        v = *(const int4*)(cnt + base);
    } else {
        if (base + 0 < n) v.x = cnt[base + 0];
        if (base + 1 < n) v.y = cnt[base + 1];
        if (base + 2 < n) v.z = cnt[base + 2];
        if (base + 3 < n) v.w = cnt[base + 3];
    }
    // pad each count to even (pair-aligned edge lists)
    v.x += v.x & 1; v.y += v.y & 1; v.z += v.z & 1; v.w += v.w & 1;
    int s = v.x + v.y + v.z + v.w;
    int incl = s;
    for (int off = 1; off < 64; off <<= 1) {
        int u = __shfl_up(incl, off);
        if (lane >= off) incl += u;
    }
    __shared__ int ws[4];
    if (lane == 63) ws[wid] = incl;
    __syncthreads();
    int woff = 0;
    for (int i = 0; i < wid; ++i) woff += ws[i];
    int excl = incl - s + woff;
    int4 o;
    o.x = excl; o.y = excl + v.x; o.z = o.y + v.y; o.w = o.z + v.z;
    if (base + 3 < n) {
        *(int4*)(locpre + base) = o;
    } else {
        if (base + 0 < n) locpre[base + 0] = o.x;
        if (base + 1 < n) locpre[base + 1] = o.y;
        if (base + 2 < n) locpre[base + 2] = o.z;
        if (base + 3 < n) locpre[base + 3] = o.w;
    }
    if (t == 255) blocksum[blockIdx.x] = excl + s;
}

// scan of block sums; also writes padded grand total to *totout (= row_ptr[n])
__global__ __launch_bounds__(64) void scan2_kernel(int* __restrict__ blocksum, int nb,
        int* __restrict__ totout) {
    int lane = threadIdx.x;
    int carry = 0;
    for (int base = 0; base < nb; base += 64) {
        int v = (base + lane < nb) ? blocksum[base + lane] : 0;
        int incl = v;
        for (int off = 1; off < 64; off <<= 1) {
            int u = __shfl_up(incl, off);
            if (lane >= off) incl += u;
        }
        int tot = __shfl(incl, 63);
        if (base + lane < nb) blocksum[base + lane] = incl - v + carry;
        carry += tot;
    }
    if (lane == 0) *totout = carry;
}

__global__ __launch_bounds__(256) void scan3_kernel(const int* __restrict__ locpre,
        const int* __restrict__ blocksum, int* __restrict__ row_ptr,
        int* __restrict__ cursor, int n) {
    int base = blockIdx.x * 1024 + threadIdx.x * 4;
    int off = blocksum[blockIdx.x];
    if (base + 3 < n) {
        int4 v = *(const int4*)(locpre + base);
        v.x += off; v.y += off; v.z += off; v.w += off;
        *(int4*)(row_ptr + base) = v;
        *(int4*)(cursor + base) = v;
    } else {
        for (int i = 0; i < 4; ++i) {
            if (base + i < n) {
                int v = locpre[base + i] + off;
                row_ptr[base + i] = v;
                cursor[base + i] = v;
            }
        }
    }
}

__global__ void scatter_kernel(const int* __restrict__ src, const int* __restrict__ dst,
        int* __restrict__ cursor, int* __restrict__ colv, int* __restrict__ srce, int E) {
    int i = blockIdx.x * blockDim.x + threadIdx.x;
    if (i < E) {
        int s = src[i];
        int p = atomicAdd(&cursor[s], 1);
        colv[p] = dst[i];
        srce[p] = s;
    }
}

// ------------------- edge records {col, w} over padded range -------------------
// srce/colv at pad slots hold poison (0xAA...), so clamp before indexing;
// padfill_kernel afterwards overwrites pad records with {0, 0.0f}.
__global__ __launch_bounds__(256) void ew_kernel(const int* __restrict__ srce,
        const int* __restrict__ colv, const float* __restrict__ asrc,
        const float* __restrict__ adst, int2* __restrict__ ewc,
        const int* __restrict__ ptot_p, int n) {
    int i = blockIdx.x * blockDim.x + threadIdx.x;
    if (i >= *ptot_p) return;
    int s = min(max(srce[i], 0), n - 1);
    int d = min(max(colv[i], 0), n - 1);
    float x = asrc[s] + adst[d];
    float lr = fmaxf(x, NEG_SLOPE * x);   // leaky_relu
    float w = __expf(-lr);
    ewc[i] = make_int2(d, __float_as_int(w));
}

// zero-weight pad records: [cursor[v], row_ptr[v+1]) per node (<=1 slot)
__global__ __launch_bounds__(256) void padfill_kernel(const int* __restrict__ cursor,
        const int* __restrict__ row_ptr, int2* __restrict__ ewc, int n) {
    int v = blockIdx.x * blockDim.x + threadIdx.x;
    if (v < n) {
        int e = row_ptr[v + 1];
        for (int p = cursor[v]; p < e; ++p) ewc[p] = make_int2(0, 0);
    }
}

// ------------------- W transpose + bf16 convert -------------------
__global__ void wt_kernel(const float* __restrict__ W, short* __restrict__ Wt) {
    int nn = blockIdx.x, k = threadIdx.x;
    Wt[nn * 256 + k] = (short)f2bf(W[k * 256 + nn]);   // Wt[n][k] = W[k][n]
}

// ------------------- GEMM: h' = h @ W (bf16 MFMA) + fused alpha dot-products ----
// h' written in SLICE-MAJOR layout: hpS[slice][node][32] (slice = col>>5), so the
// aggregate's XCD-affine slices are each contiguous 3.2MB (fits one XCD L2).
template<bool IN_BF16>
__global__ __launch_bounds__(256) void gemm_kernel(const void* __restrict__ hin,
        const short* __restrict__ Wt, unsigned short* __restrict__ hpS,
        const float* __restrict__ af, float* __restrict__ asrc,
        float* __restrict__ adst, int M) {
    __shared__ short As[64 * 40];    // 64 rows x 32 k, pad to 40
    __shared__ short Bt[256 * 40];   // 256 n-rows x 32 k, pad to 40
    int tid = threadIdx.x;
    int lane = tid & 63, w = tid >> 6;
    int m0 = blockIdx.x * 64;
    size_t Ns = (size_t)M * 32;      // slice stride

    f32x4 acc[16];
#pragma unroll
    for (int t = 0; t < 16; ++t) acc[t] = (f32x4){0.f, 0.f, 0.f, 0.f};

    int ar = tid >> 2;          // 0..63
    int ac = (tid & 3) * 8;     // 0,8,16,24
    int agrow = m0 + ar;

    for (int kk = 0; kk < 256; kk += 32) {
        short8v av = (short8v){0,0,0,0,0,0,0,0};
        if constexpr (IN_BF16) {
            if (agrow < M)
                av = *(const short8v*)((const short*)hin + (size_t)agrow * 256 + kk + ac);
        } else {
            if (agrow < M) {
                const float* s = (const float*)hin + (size_t)agrow * 256 + kk + ac;
                float4 v0 = *(const float4*)s;
                float4 v1 = *(const float4*)(s + 4);
                av[0] = (short)f2bf(v0.x); av[1] = (short)f2bf(v0.y);
                av[2] = (short)f2bf(v0.z); av[3] = (short)f2bf(v0.w);
                av[4] = (short)f2bf(v1.x); av[5] = (short)f2bf(v1.y);
                av[6] = (short)f2bf(v1.z); av[7] = (short)f2bf(v1.w);
            }
        }
        *(short8v*)&As[ar * 40 + ac] = av;
        {
            const short* s = Wt + (size_t)tid * 256 + kk;
#pragma unroll
            for (int i = 0; i < 4; ++i)
                *(short8v*)&Bt[tid * 40 + i * 8] = *(const short8v*)(s + i * 8);
        }
        __syncthreads();
        short8v a = *(const short8v*)&As[(16 * w + (lane & 15)) * 40 + (lane >> 4) * 8];
#pragma unroll
        for (int t = 0; t < 16; ++t) {
            short8v b = *(const short8v*)&Bt[(16 * t + (lane & 15)) * 40 + (lane >> 4) * 8];
            acc[t] = __builtin_amdgcn_mfma_f32_16x16x32_bf16(a, b, acc[t], 0, 0, 0);
        }
        __syncthreads();
    }
    int r0 = 16 * w + (lane >> 4) * 4;
    int c0 = lane & 15;
    float a_s[16], a_d[16];
#pragma unroll
    for (int t = 0; t < 16; ++t) {
        a_s[t] = af[16 * t + c0];
        a_d[t] = af[256 + 16 * t + c0];
    }
#pragma unroll
    for (int j = 0; j < 4; ++j) {
        int grow = m0 + r0 + j;
        float ssrc = 0.f, sdst = 0.f;
#pragma unroll
        for (int t = 0; t < 16; ++t) {
            float cv = acc[t][j];
            ssrc = fmaf(cv, a_s[t], ssrc);
            sdst = fmaf(cv, a_d[t], sdst);
            int col = 16 * t + c0;
            if (grow < M)
                hpS[(size_t)(col >> 5) * Ns + (size_t)grow * 32 + (col & 31)] = f2bf(cv);
        }
        for (int off = 1; off < 16; off <<= 1) {
            ssrc += __shfl_xor(ssrc, off);
            sdst += __shfl_xor(sdst, off);
        }
        if (c0 == 0 && grow < M) { asrc[grow] = ssrc; adst[grow] = sdst; }
    }
}

// ------------------- aggregation: (node, slice) per wave, XCD-affine slices ----
// slice = blockIdx.x % 8 -> consecutive blocks hit consecutive XCDs, so each
// XCD's L2 only ever gathers from ONE 3.2MB slice (L2-resident after warmup).
// Lanes 0-31 process edge 2k, lanes 32-63 edge 2k+1 (same 32 cols); halves are
// combined with shfl_xor(32) at the end. Pad records have w=0 (no guards).
template<bool OUT_BF16>
__global__ __launch_bounds__(256) void aggregate_kernel(const int* __restrict__ row_ptr,
        const int2* __restrict__ ewc, const unsigned short* __restrict__ hpS,
        void* __restrict__ outp, int n) {
    int bid = blockIdx.x;
    int slice = bid & 7;
    int node = (bid >> 3) * 4 + (threadIdx.x >> 6);
    int lane = threadIdx.x & 63;
    if (node >= n) return;
    int beg = row_ptr[node], end = row_ptr[node + 1];   // both even
    const unsigned short* __restrict__ base = hpS + (size_t)slice * ((size_t)n * 32);
    int c = lane & 31;
    int hi = lane >> 5;
    float acc = 0.f, rs = 0.f;
    int e = beg;
    for (; e + 8 <= end; e += 8) {   // 4 pairs = 8 edges, 4 gathers in flight
        int4 p0 = *(const int4*)(ewc + e);
        int4 p1 = *(const int4*)(ewc + e + 2);
        int4 p2 = *(const int4*)(ewc + e + 4);
        int4 p3 = *(const int4*)(ewc + e + 6);
        int j0 = hi ? p0.z : p0.x; float w0 = __int_as_float(hi ? p0.w : p0.y);
        int j1 = hi ? p1.z : p1.x; float w1 = __int_as_float(hi ? p1.w : p1.y);
        int j2 = hi ? p2.z : p2.x; float w2 = __int_as_float(hi ? p2.w : p2.y);
        int j3 = hi ? p3.z : p3.x; float w3 = __int_as_float(hi ? p3.w : p3.y);
        unsigned short q0 = base[(unsigned)j0 * 32 + c];
        unsigned short q1 = base[(unsigned)j1 * 32 + c];
        unsigned short q2 = base[(unsigned)j2 * 32 + c];
        unsigned short q3 = base[(unsigned)j3 * 32 + c];
        acc = fmaf(w0, bf2f(q0), acc); rs += w0;
        acc = fmaf(w1, bf2f(q1), acc); rs += w1;
        acc = fmaf(w2, bf2f(q2), acc); rs += w2;
        acc = fmaf(w3, bf2f(q3), acc); rs += w3;
    }
    for (; e < end; e += 2) {        // leftover pairs
        int4 p0 = *(const int4*)(ewc + e);
        int j0 = hi ? p0.z : p0.x; float w0 = __int_as_float(hi ? p0.w : p0.y);
        unsigned short q0 = base[(unsigned)j0 * 32 + c];
        acc = fmaf(w0, bf2f(q0), acc); rs += w0;
    }
    acc += __shfl_xor(acc, 32);
    rs  += __shfl_xor(rs, 32);
    if (hi == 0) {
        float v = acc / (rs + EPS_);
        v = v > 0.f ? v : __expf(v) - 1.f;   // ELU
        if constexpr (OUT_BF16)
            ((unsigned short*)outp)[(size_t)node * 256 + slice * 32 + c] = f2bf(v);
        else
            ((float*)outp)[(size_t)node * 256 + slice * 32 + c] = v;
    }
}

extern "C" void kernel_launch(void* const* d_in, const int* in_sizes, int n_in,
                              void* d_out, int out_size, void* d_ws, size_t ws_size,
                              hipStream_t stream) {
    const float* sr_emb = (const float*)d_in[0];
    const float* tg_emb = (const float*)d_in[1];
    const float* W1 = (const float*)d_in[2];
    const float* a1 = (const float*)d_in[3];
    const float* W2 = (const float*)d_in[4];
    const float* a2 = (const float*)d_in[5];
    const int* adj_sr = (const int*)d_in[6];
    const int* adj_tg = (const int*)d_in[7];
    int N = in_sizes[0] / 256;
    int E = in_sizes[6] / 2;

    char* p = (char*)d_ws;
    auto alloc = [&](size_t bytes) -> void* {
        void* r = (void*)p;
        p += (bytes + 255) & ~(size_t)255;
        return r;
    };
    int nb = (N + 1023) / 1024;
    int EP = E + N + 16;                       // padded-edge capacity
    int* cnt      = (int*)alloc((size_t)N * 4);
    int* row_ptr  = (int*)alloc((size_t)(N + 1) * 4);
    int* cursor   = (int*)alloc((size_t)N * 4);
    int* locpre   = (int*)alloc((size_t)N * 4);
    int* blocksum = (int*)alloc((size_t)nb * 4);
    int* colv     = (int*)alloc((size_t)EP * 4);
    int* srce     = (int*)alloc((size_t)EP * 4);
    int2* ewc     = (int2*)alloc((size_t)EP * 8);
    short* Wt1    = (short*)alloc(256 * 256 * 2);
    short* Wt2    = (short*)alloc(256 * 256 * 2);
    unsigned short* hpS = (unsigned short*)alloc((size_t)N * 256 * 2);  // slice-major
    float* asrc   = (float*)alloc((size_t)N * 4);
    float* adst   = (float*)alloc((size_t)N * 4);
    short* tmp    = (short*)alloc((size_t)N * 256 * 2);

    wt_kernel<<<256, 256, 0, stream>>>(W1, Wt1);
    wt_kernel<<<256, 256, 0, stream>>>(W2, Wt2);

    int gemm_grid = (N + 63) / 64;
    int agg_grid = 8 * ((N + 3) / 4);   // slice = bid%8 (XCD-affine), 4 nodes/block
    int e_grid = (E + 255) / 256;
    int ep_grid = (EP + 255) / 256;
    int n_grid = (N + 255) / 256;

    for (int g = 0; g < 2; ++g) {
        const int* srcv = (g == 0 ? adj_sr : adj_tg);
        const int* dstv = srcv + E;
        const float* emb = (g == 0 ? sr_emb : tg_emb);
        float* outg = (float*)d_out + (size_t)g * N * 256;

        hipMemsetAsync(cnt, 0, (size_t)N * 4, stream);
        hist_kernel<<<e_grid, 256, 0, stream>>>(srcv, cnt, E);
        scan1_kernel<<<nb, 256, 0, stream>>>(cnt, locpre, blocksum, N);
        scan2_kernel<<<1, 64, 0, stream>>>(blocksum, nb, row_ptr + N);
        scan3_kernel<<<nb, 256, 0, stream>>>(locpre, blocksum, row_ptr, cursor, N);
        scatter_kernel<<<e_grid, 256, 0, stream>>>(srcv, dstv, cursor, colv, srce, E);

        // layer 1: f32 input -> bf16 tmp (alpha fused into gemm epilogue)
        gemm_kernel<false><<<gemm_grid, 256, 0, stream>>>(emb, Wt1, hpS, a1, asrc, adst, N);
        ew_kernel<<<ep_grid, 256, 0, stream>>>(srce, colv, asrc, adst, ewc, row_ptr + N, N);
        padfill_kernel<<<n_grid, 256, 0, stream>>>(cursor, row_ptr, ewc, N);
        aggregate_kernel<true><<<agg_grid, 256, 0, stream>>>(row_ptr, ewc, hpS, tmp, N);
        // layer 2: bf16 input -> f32 out
        gemm_kernel<true><<<gemm_grid, 256, 0, stream>>>(tmp, Wt2, hpS, a2, asrc, adst, N);
        ew_kernel<<<ep_grid, 256, 0, stream>>>(srce, colv, asrc, adst, ewc, row_ptr + N, N);
        padfill_kernel<<<n_grid, 256, 0, stream>>>(cursor, row_ptr, ewc, N);
        aggregate_kernel<false><<<agg_grid, 256, 0, stream>>>(row_ptr, ewc, hpS, outg, N);
    }
}

// Round 7
// 920.818 us; speedup vs baseline: 1.1391x; 1.1391x over previous
//
#include <hip/hip_runtime.h>

#define NEG_SLOPE 0.2f
#define EPS_ 1e-9f

typedef __attribute__((ext_vector_type(8))) short short8v;
typedef __attribute__((ext_vector_type(4))) float f32x4;

__device__ __forceinline__ float bf2f(unsigned short u) {
    return __uint_as_float(((unsigned)u) << 16);
}
__device__ __forceinline__ unsigned short f2bf(float f) {
    unsigned u = __float_as_uint(f);
    u = u + 0x7FFFu + ((u >> 16) & 1u);   // round-to-nearest-even
    return (unsigned short)(u >> 16);
}

// ------------------- CSR build (node edge-lists PADDED to multiple of 8) -------
__global__ void hist_kernel(const int* __restrict__ src, int* __restrict__ cnt, int E) {
    int i = blockIdx.x * blockDim.x + threadIdx.x;
    if (i < E) atomicAdd(&cnt[src[i]], 1);
}

__global__ __launch_bounds__(256) void scan1_kernel(const int* __restrict__ cnt,
        int* __restrict__ locpre, int* __restrict__ blocksum, int n) {
    int t = threadIdx.x;
    int lane = t & 63, wid = t >> 6;
    int base = blockIdx.x * 1024 + t * 4;
    int4 v = {0, 0, 0, 0};
    if (base + 3 < n) {
        v = *(const int4*)(cnt + base);
    } else {
        if (base + 0 < n) v.x = cnt[base + 0];
        if (base + 1 < n) v.y = cnt[base + 1];
        if (base + 2 < n) v.z = cnt[base + 2];
        if (base + 3 < n) v.w = cnt[base + 3];
    }
    // pad each count up to a multiple of 8 (guard-free 8-edge chunks in aggregate)
    v.x = (v.x + 7) & ~7; v.y = (v.y + 7) & ~7;
    v.z = (v.z + 7) & ~7; v.w = (v.w + 7) & ~7;
    int s = v.x + v.y + v.z + v.w;
    int incl = s;
    for (int off = 1; off < 64; off <<= 1) {
        int u = __shfl_up(incl, off);
        if (lane >= off) incl += u;
    }
    __shared__ int ws[4];
    if (lane == 63) ws[wid] = incl;
    __syncthreads();
    int woff = 0;
    for (int i = 0; i < wid; ++i) woff += ws[i];
    int excl = incl - s + woff;
    int4 o;
    o.x = excl; o.y = excl + v.x; o.z = o.y + v.y; o.w = o.z + v.z;
    if (base + 3 < n) {
        *(int4*)(locpre + base) = o;
    } else {
        if (base + 0 < n) locpre[base + 0] = o.x;
        if (base + 1 < n) locpre[base + 1] = o.y;
        if (base + 2 < n) locpre[base + 2] = o.z;
        if (base + 3 < n) locpre[base + 3] = o.w;
    }
    if (t == 255) blocksum[blockIdx.x] = excl + s;
}

// scan of block sums; also writes padded grand total to *totout (= row_ptr[n])
__global__ __launch_bounds__(64) void scan2_kernel(int* __restrict__ blocksum, int nb,
        int* __restrict__ totout) {
    int lane = threadIdx.x;
    int carry = 0;
    for (int base = 0; base < nb; base += 64) {
        int v = (base + lane < nb) ? blocksum[base + lane] : 0;
        int incl = v;
        for (int off = 1; off < 64; off <<= 1) {
            int u = __shfl_up(incl, off);
            if (lane >= off) incl += u;
        }
        int tot = __shfl(incl, 63);
        if (base + lane < nb) blocksum[base + lane] = incl - v + carry;
        carry += tot;
    }
    if (lane == 0) *totout = carry;
}

__global__ __launch_bounds__(256) void scan3_kernel(const int* __restrict__ locpre,
        const int* __restrict__ blocksum, int* __restrict__ row_ptr,
        int* __restrict__ cursor, int n) {
    int base = blockIdx.x * 1024 + threadIdx.x * 4;
    int off = blocksum[blockIdx.x];
    if (base + 3 < n) {
        int4 v = *(const int4*)(locpre + base);
        v.x += off; v.y += off; v.z += off; v.w += off;
        *(int4*)(row_ptr + base) = v;
        *(int4*)(cursor + base) = v;
    } else {
        for (int i = 0; i < 4; ++i) {
            if (base + i < n) {
                int v = locpre[base + i] + off;
                row_ptr[base + i] = v;
                cursor[base + i] = v;
            }
        }
    }
}

__global__ void scatter_kernel(const int* __restrict__ src, const int* __restrict__ dst,
        int* __restrict__ cursor, int* __restrict__ colv, int* __restrict__ srce, int E) {
    int i = blockIdx.x * blockDim.x + threadIdx.x;
    if (i < E) {
        int s = src[i];
        int p = atomicAdd(&cursor[s], 1);
        colv[p] = dst[i];
        srce[p] = s;
    }
}

// ------------------- edge records {col, w} over padded range -------------------
// srce/colv at pad slots hold garbage, so clamp before indexing;
// padfill_kernel afterwards overwrites pad records with {0, 0.0f}.
__global__ __launch_bounds__(256) void ew_kernel(const int* __restrict__ srce,
        const int* __restrict__ colv, const float* __restrict__ asrc,
        const float* __restrict__ adst, int2* __restrict__ ewc,
        const int* __restrict__ ptot_p, int n) {
    int i = blockIdx.x * blockDim.x + threadIdx.x;
    if (i >= *ptot_p) return;
    int s = min(max(srce[i], 0), n - 1);
    int d = min(max(colv[i], 0), n - 1);
    float x = asrc[s] + adst[d];
    float lr = fmaxf(x, NEG_SLOPE * x);   // leaky_relu
    float w = __expf(-lr);
    ewc[i] = make_int2(d, __float_as_int(w));
}

// zero-weight pad records: [cursor[v], row_ptr[v+1]) per node (<=7 slots)
__global__ __launch_bounds__(256) void padfill_kernel(const int* __restrict__ cursor,
        const int* __restrict__ row_ptr, int2* __restrict__ ewc, int n) {
    int v = blockIdx.x * blockDim.x + threadIdx.x;
    if (v < n) {
        int e = row_ptr[v + 1];
        for (int p = cursor[v]; p < e; ++p) ewc[p] = make_int2(0, 0);
    }
}

// ------------------- W transpose + bf16 convert -------------------
__global__ void wt_kernel(const float* __restrict__ W, short* __restrict__ Wt) {
    int nn = blockIdx.x, k = threadIdx.x;
    Wt[nn * 256 + k] = (short)f2bf(W[k * 256 + nn]);   // Wt[n][k] = W[k][n]
}

// ------------------- GEMM: h' = h @ W (bf16 MFMA) + fused alpha dot-products ----
// h' written SLICE-MAJOR: hpS[slice][node][32] (slice = col>>5) for the
// XCD-affine aggregate (each slice = 3.2MB, fits one XCD's 4MB L2).
template<bool IN_BF16>
__global__ __launch_bounds__(256) void gemm_kernel(const void* __restrict__ hin,
        const short* __restrict__ Wt, unsigned short* __restrict__ hpS,
        const float* __restrict__ af, float* __restrict__ asrc,
        float* __restrict__ adst, int M) {
    __shared__ short As[64 * 40];    // 64 rows x 32 k, pad to 40
    __shared__ short Bt[256 * 40];   // 256 n-rows x 32 k, pad to 40
    int tid = threadIdx.x;
    int lane = tid & 63, w = tid >> 6;
    int m0 = blockIdx.x * 64;
    size_t Ns = (size_t)M * 32;      // slice stride

    f32x4 acc[16];
#pragma unroll
    for (int t = 0; t < 16; ++t) acc[t] = (f32x4){0.f, 0.f, 0.f, 0.f};

    int ar = tid >> 2;          // 0..63
    int ac = (tid & 3) * 8;     // 0,8,16,24
    int agrow = m0 + ar;

    for (int kk = 0; kk < 256; kk += 32) {
        short8v av = (short8v){0,0,0,0,0,0,0,0};
        if constexpr (IN_BF16) {
            if (agrow < M)
                av = *(const short8v*)((const short*)hin + (size_t)agrow * 256 + kk + ac);
        } else {
            if (agrow < M) {
                const float* s = (const float*)hin + (size_t)agrow * 256 + kk + ac;
                float4 v0 = *(const float4*)s;
                float4 v1 = *(const float4*)(s + 4);
                av[0] = (short)f2bf(v0.x); av[1] = (short)f2bf(v0.y);
                av[2] = (short)f2bf(v0.z); av[3] = (short)f2bf(v0.w);
                av[4] = (short)f2bf(v1.x); av[5] = (short)f2bf(v1.y);
                av[6] = (short)f2bf(v1.z); av[7] = (short)f2bf(v1.w);
            }
        }
        *(short8v*)&As[ar * 40 + ac] = av;
        {
            const short* s = Wt + (size_t)tid * 256 + kk;
#pragma unroll
            for (int i = 0; i < 4; ++i)
                *(short8v*)&Bt[tid * 40 + i * 8] = *(const short8v*)(s + i * 8);
        }
        __syncthreads();
        short8v a = *(const short8v*)&As[(16 * w + (lane & 15)) * 40 + (lane >> 4) * 8];
#pragma unroll
        for (int t = 0; t < 16; ++t) {
            short8v b = *(const short8v*)&Bt[(16 * t + (lane & 15)) * 40 + (lane >> 4) * 8];
            acc[t] = __builtin_amdgcn_mfma_f32_16x16x32_bf16(a, b, acc[t], 0, 0, 0);
        }
        __syncthreads();
    }
    int r0 = 16 * w + (lane >> 4) * 4;
    int c0 = lane & 15;
    float a_s[16], a_d[16];
#pragma unroll
    for (int t = 0; t < 16; ++t) {
        a_s[t] = af[16 * t + c0];
        a_d[t] = af[256 + 16 * t + c0];
    }
#pragma unroll
    for (int j = 0; j < 4; ++j) {
        int grow = m0 + r0 + j;
        float ssrc = 0.f, sdst = 0.f;
#pragma unroll
        for (int t = 0; t < 16; ++t) {
            float cv = acc[t][j];
            ssrc = fmaf(cv, a_s[t], ssrc);
            sdst = fmaf(cv, a_d[t], sdst);
            int col = 16 * t + c0;
            if (grow < M)
                hpS[(size_t)(col >> 5) * Ns + (size_t)grow * 32 + (col & 31)] = f2bf(cv);
        }
        for (int off = 1; off < 16; off <<= 1) {
            ssrc += __shfl_xor(ssrc, off);
            sdst += __shfl_xor(sdst, off);
        }
        if (c0 == 0 && grow < M) { asrc[grow] = ssrc; adst[grow] = sdst; }
    }
}

// ------------------- aggregation: (node, slice) per wave, XCD-affine slices ----
// slice = blockIdx.x & 7 -> consecutive blocks hit consecutive XCDs; each XCD
// only gathers from ONE 3.2MB slice (L2-resident).  Instruction shape fixed vs
// R6: lane l covers edge-group g=l>>3, cols (l&7)*4, so ONE ushort4 gather inst
// moves 8 rows x 64B = 512B (R3-level efficiency at R6-level locality).
// Edge lists are multiples of 8 with w=0 pads -> zero guards in the loop.
template<bool OUT_BF16>
__global__ __launch_bounds__(256) void aggregate_kernel(const int* __restrict__ row_ptr,
        const int2* __restrict__ ewc, const unsigned short* __restrict__ hpS,
        void* __restrict__ outp, int n) {
    int bid = blockIdx.x;
    int slice = bid & 7;
    int node = (bid >> 3) * 4 + (threadIdx.x >> 6);
    int lane = threadIdx.x & 63;
    if (node >= n) return;
    int beg = row_ptr[node], end = row_ptr[node + 1];   // multiples of 8
    const unsigned short* __restrict__ base = hpS + (size_t)slice * ((size_t)n * 32);
    int g = lane >> 3;          // edge sub-index within chunk
    int c4 = (lane & 7) * 4;    // column offset within slice
    float acc0 = 0.f, acc1 = 0.f, acc2 = 0.f, acc3 = 0.f, rs = 0.f;
    for (int e = beg; e < end; e += 8) {
        int2 pw = ewc[e + g];                 // 8 distinct addrs, HW broadcast
        int j = pw.x;
        float w = __int_as_float(pw.y);
        ushort4 q = *(const ushort4*)(base + (size_t)(unsigned)j * 32 + c4);
        acc0 = fmaf(w, bf2f(q.x), acc0);
        acc1 = fmaf(w, bf2f(q.y), acc1);
        acc2 = fmaf(w, bf2f(q.z), acc2);
        acc3 = fmaf(w, bf2f(q.w), acc3);
        rs += w;
    }
    // reduce the 8 edge-groups (lanes sharing lane&7)
    for (int off = 8; off < 64; off <<= 1) {
        acc0 += __shfl_xor(acc0, off);
        acc1 += __shfl_xor(acc1, off);
        acc2 += __shfl_xor(acc2, off);
        acc3 += __shfl_xor(acc3, off);
        rs   += __shfl_xor(rs, off);
    }
    if (g == 0) {
        float inv = 1.f / (rs + EPS_);
        float v0 = acc0 * inv, v1 = acc1 * inv, v2 = acc2 * inv, v3 = acc3 * inv;
        v0 = v0 > 0.f ? v0 : __expf(v0) - 1.f;   // ELU
        v1 = v1 > 0.f ? v1 : __expf(v1) - 1.f;
        v2 = v2 > 0.f ? v2 : __expf(v2) - 1.f;
        v3 = v3 > 0.f ? v3 : __expf(v3) - 1.f;
        size_t o = (size_t)node * 256 + slice * 32 + c4;
        if constexpr (OUT_BF16) {
            ushort4 ov;
            ov.x = f2bf(v0); ov.y = f2bf(v1); ov.z = f2bf(v2); ov.w = f2bf(v3);
            *(ushort4*)((unsigned short*)outp + o) = ov;
        } else {
            float4 ov = {v0, v1, v2, v3};
            *(float4*)((float*)outp + o) = ov;
        }
    }
}

extern "C" void kernel_launch(void* const* d_in, const int* in_sizes, int n_in,
                              void* d_out, int out_size, void* d_ws, size_t ws_size,
                              hipStream_t stream) {
    const float* sr_emb = (const float*)d_in[0];
    const float* tg_emb = (const float*)d_in[1];
    const float* W1 = (const float*)d_in[2];
    const float* a1 = (const float*)d_in[3];
    const float* W2 = (const float*)d_in[4];
    const float* a2 = (const float*)d_in[5];
    const int* adj_sr = (const int*)d_in[6];
    const int* adj_tg = (const int*)d_in[7];
    int N = in_sizes[0] / 256;
    int E = in_sizes[6] / 2;

    char* p = (char*)d_ws;
    auto alloc = [&](size_t bytes) -> void* {
        void* r = (void*)p;
        p += (bytes + 255) & ~(size_t)255;
        return r;
    };
    int nb = (N + 1023) / 1024;
    int EP = E + 8 * N + 64;                   // padded-edge capacity
    int* cnt      = (int*)alloc((size_t)N * 4);
    int* row_ptr  = (int*)alloc((size_t)(N + 1) * 4);
    int* cursor   = (int*)alloc((size_t)N * 4);
    int* locpre   = (int*)alloc((size_t)N * 4);
    int* blocksum = (int*)alloc((size_t)nb * 4);
    int* colv     = (int*)alloc((size_t)EP * 4);
    int* srce     = (int*)alloc((size_t)EP * 4);
    int2* ewc     = (int2*)alloc((size_t)EP * 8);
    short* Wt1    = (short*)alloc(256 * 256 * 2);
    short* Wt2    = (short*)alloc(256 * 256 * 2);
    unsigned short* hpS = (unsigned short*)alloc((size_t)N * 256 * 2);  // slice-major
    float* asrc   = (float*)alloc((size_t)N * 4);
    float* adst   = (float*)alloc((size_t)N * 4);
    short* tmp    = (short*)alloc((size_t)N * 256 * 2);

    wt_kernel<<<256, 256, 0, stream>>>(W1, Wt1);
    wt_kernel<<<256, 256, 0, stream>>>(W2, Wt2);

    int gemm_grid = (N + 63) / 64;
    int agg_grid = 8 * ((N + 3) / 4);   // slice = bid&7 (XCD-affine), 4 nodes/block
    int e_grid = (E + 255) / 256;
    int ep_grid = (EP + 255) / 256;
    int n_grid = (N + 255) / 256;

    for (int g = 0; g < 2; ++g) {
        const int* srcv = (g == 0 ? adj_sr : adj_tg);
        const int* dstv = srcv + E;
        const float* emb = (g == 0 ? sr_emb : tg_emb);
        float* outg = (float*)d_out + (size_t)g * N * 256;

        hipMemsetAsync(cnt, 0, (size_t)N * 4, stream);
        hist_kernel<<<e_grid, 256, 0, stream>>>(srcv, cnt, E);
        scan1_kernel<<<nb, 256, 0, stream>>>(cnt, locpre, blocksum, N);
        scan2_kernel<<<1, 64, 0, stream>>>(blocksum, nb, row_ptr + N);
        scan3_kernel<<<nb, 256, 0, stream>>>(locpre, blocksum, row_ptr, cursor, N);
        scatter_kernel<<<e_grid, 256, 0, stream>>>(srcv, dstv, cursor, colv, srce, E);

        // layer 1: f32 input -> bf16 tmp (alpha fused into gemm epilogue)
        gemm_kernel<false><<<gemm_grid, 256, 0, stream>>>(emb, Wt1, hpS, a1, asrc, adst, N);
        ew_kernel<<<ep_grid, 256, 0, stream>>>(srce, colv, asrc, adst, ewc, row_ptr + N, N);
        padfill_kernel<<<n_grid, 256, 0, stream>>>(cursor, row_ptr, ewc, N);
        aggregate_kernel<true><<<agg_grid, 256, 0, stream>>>(row_ptr, ewc, hpS, tmp, N);
        // layer 2: bf16 input -> f32 out
        gemm_kernel<true><<<gemm_grid, 256, 0, stream>>>(tmp, Wt2, hpS, a2, asrc, adst, N);
        ew_kernel<<<ep_grid, 256, 0, stream>>>(srce, colv, asrc, adst, ewc, row_ptr + N, N);
        padfill_kernel<<<n_grid, 256, 0, stream>>>(cursor, row_ptr, ewc, N);
        aggregate_kernel<false><<<agg_grid, 256, 0, stream>>>(row_ptr, ewc, hpS, outg, N);
    }
}

// Round 8
// 806.544 us; speedup vs baseline: 1.3005x; 1.1417x over previous
//
#include <hip/hip_runtime.h>

#define NEG_SLOPE 0.2f
#define EPS_ 1e-9f

typedef __attribute__((ext_vector_type(8))) short short8v;
typedef __attribute__((ext_vector_type(4))) float f32x4;

__device__ __forceinline__ float bf2f(unsigned short u) {
    return __uint_as_float(((unsigned)u) << 16);
}
__device__ __forceinline__ unsigned short f2bf(float f) {
    unsigned u = __float_as_uint(f);
    u = u + 0x7FFFu + ((u >> 16) & 1u);   // round-to-nearest-even
    return (unsigned short)(u >> 16);
}

// ------------------- CSR build (exact, no padding) -------------------
__global__ void hist_kernel(const int* __restrict__ src, int* __restrict__ cnt, int E) {
    int i = blockIdx.x * blockDim.x + threadIdx.x;
    if (i < E) atomicAdd(&cnt[src[i]], 1);
}

__global__ __launch_bounds__(256) void scan1_kernel(const int* __restrict__ cnt,
        int* __restrict__ locpre, int* __restrict__ blocksum, int n) {
    int t = threadIdx.x;
    int lane = t & 63, wid = t >> 6;
    int base = blockIdx.x * 1024 + t * 4;
    int4 v = {0, 0, 0, 0};
    if (base + 3 < n) {
        v = *(const int4*)(cnt + base);
    } else {
        if (base + 0 < n) v.x = cnt[base + 0];
        if (base + 1 < n) v.y = cnt[base + 1];
        if (base + 2 < n) v.z = cnt[base + 2];
        if (base + 3 < n) v.w = cnt[base + 3];
    }
    int s = v.x + v.y + v.z + v.w;
    int incl = s;
    for (int off = 1; off < 64; off <<= 1) {
        int u = __shfl_up(incl, off);
        if (lane >= off) incl += u;
    }
    __shared__ int ws[4];
    if (lane == 63) ws[wid] = incl;
    __syncthreads();
    int woff = 0;
    for (int i = 0; i < wid; ++i) woff += ws[i];
    int excl = incl - s + woff;
    int4 o;
    o.x = excl; o.y = excl + v.x; o.z = o.y + v.y; o.w = o.z + v.z;
    if (base + 3 < n) {
        *(int4*)(locpre + base) = o;
    } else {
        if (base + 0 < n) locpre[base + 0] = o.x;
        if (base + 1 < n) locpre[base + 1] = o.y;
        if (base + 2 < n) locpre[base + 2] = o.z;
        if (base + 3 < n) locpre[base + 3] = o.w;
    }
    if (t == 255) blocksum[blockIdx.x] = excl + s;
}

// scan of block sums; also writes grand total (=E) to *totout (= row_ptr[n])
__global__ __launch_bounds__(64) void scan2_kernel(int* __restrict__ blocksum, int nb,
        int* __restrict__ totout) {
    int lane = threadIdx.x;
    int carry = 0;
    for (int base = 0; base < nb; base += 64) {
        int v = (base + lane < nb) ? blocksum[base + lane] : 0;
        int incl = v;
        for (int off = 1; off < 64; off <<= 1) {
            int u = __shfl_up(incl, off);
            if (lane >= off) incl += u;
        }
        int tot = __shfl(incl, 63);
        if (base + lane < nb) blocksum[base + lane] = incl - v + carry;
        carry += tot;
    }
    if (lane == 0) *totout = carry;
}

__global__ __launch_bounds__(256) void scan3_kernel(const int* __restrict__ locpre,
        const int* __restrict__ blocksum, int* __restrict__ row_ptr,
        int* __restrict__ cursor, int n) {
    int base = blockIdx.x * 1024 + threadIdx.x * 4;
    int off = blocksum[blockIdx.x];
    if (base + 3 < n) {
        int4 v = *(const int4*)(locpre + base);
        v.x += off; v.y += off; v.z += off; v.w += off;
        *(int4*)(row_ptr + base) = v;
        *(int4*)(cursor + base) = v;
    } else {
        for (int i = 0; i < 4; ++i) {
            if (base + i < n) {
                int v = locpre[base + i] + off;
                row_ptr[base + i] = v;
                cursor[base + i] = v;
            }
        }
    }
}

__global__ void scatter_kernel(const int* __restrict__ src, const int* __restrict__ dst,
        int* __restrict__ cursor, int* __restrict__ colv, int* __restrict__ srce, int E) {
    int i = blockIdx.x * blockDim.x + threadIdx.x;
    if (i < E) {
        int s = src[i];
        int p = atomicAdd(&cursor[s], 1);
        colv[p] = dst[i];
        srce[p] = s;
    }
}

// ------------------- edge records {col, w}, CSR order, exact range -------------
__global__ __launch_bounds__(256) void ew_kernel(const int* __restrict__ srce,
        const int* __restrict__ colv, const float* __restrict__ asrc,
        const float* __restrict__ adst, int2* __restrict__ ewc, int E) {
    int i = blockIdx.x * blockDim.x + threadIdx.x;
    if (i < E) {
        int d = colv[i];
        float x = asrc[srce[i]] + adst[d];
        float lr = fmaxf(x, NEG_SLOPE * x);   // leaky_relu
        ewc[i] = make_int2(d, __float_as_int(__expf(-lr)));
    }
}

// ------------------- W transpose + bf16 convert -------------------
__global__ void wt_kernel(const float* __restrict__ W, short* __restrict__ Wt) {
    int nn = blockIdx.x, k = threadIdx.x;
    Wt[nn * 256 + k] = (short)f2bf(W[k * 256 + nn]);   // Wt[n][k] = W[k][n]
}

// ------------------- GEMM: h' = h @ W (bf16 MFMA) + fused alpha dot-products ----
// h' written SLICE-MAJOR: hpS[slice][node][32] (slice = col>>5) for the
// XCD-affine aggregate (each slice = 3.2MB, fits one XCD's 4MB L2).
template<bool IN_BF16>
__global__ __launch_bounds__(256) void gemm_kernel(const void* __restrict__ hin,
        const short* __restrict__ Wt, unsigned short* __restrict__ hpS,
        const float* __restrict__ af, float* __restrict__ asrc,
        float* __restrict__ adst, int M) {
    __shared__ short As[64 * 40];    // 64 rows x 32 k, pad to 40
    __shared__ short Bt[256 * 40];   // 256 n-rows x 32 k, pad to 40
    int tid = threadIdx.x;
    int lane = tid & 63, w = tid >> 6;
    int m0 = blockIdx.x * 64;
    size_t Ns = (size_t)M * 32;      // slice stride

    f32x4 acc[16];
#pragma unroll
    for (int t = 0; t < 16; ++t) acc[t] = (f32x4){0.f, 0.f, 0.f, 0.f};

    int ar = tid >> 2;          // 0..63
    int ac = (tid & 3) * 8;     // 0,8,16,24
    int agrow = m0 + ar;

    for (int kk = 0; kk < 256; kk += 32) {
        short8v av = (short8v){0,0,0,0,0,0,0,0};
        if constexpr (IN_BF16) {
            if (agrow < M)
                av = *(const short8v*)((const short*)hin + (size_t)agrow * 256 + kk + ac);
        } else {
            if (agrow < M) {
                const float* s = (const float*)hin + (size_t)agrow * 256 + kk + ac;
                float4 v0 = *(const float4*)s;
                float4 v1 = *(const float4*)(s + 4);
                av[0] = (short)f2bf(v0.x); av[1] = (short)f2bf(v0.y);
                av[2] = (short)f2bf(v0.z); av[3] = (short)f2bf(v0.w);
                av[4] = (short)f2bf(v1.x); av[5] = (short)f2bf(v1.y);
                av[6] = (short)f2bf(v1.z); av[7] = (short)f2bf(v1.w);
            }
        }
        *(short8v*)&As[ar * 40 + ac] = av;
        {
            const short* s = Wt + (size_t)tid * 256 + kk;
#pragma unroll
            for (int i = 0; i < 4; ++i)
                *(short8v*)&Bt[tid * 40 + i * 8] = *(const short8v*)(s + i * 8);
        }
        __syncthreads();
        short8v a = *(const short8v*)&As[(16 * w + (lane & 15)) * 40 + (lane >> 4) * 8];
#pragma unroll
        for (int t = 0; t < 16; ++t) {
            short8v b = *(const short8v*)&Bt[(16 * t + (lane & 15)) * 40 + (lane >> 4) * 8];
            acc[t] = __builtin_amdgcn_mfma_f32_16x16x32_bf16(a, b, acc[t], 0, 0, 0);
        }
        __syncthreads();
    }
    int r0 = 16 * w + (lane >> 4) * 4;
    int c0 = lane & 15;
    float a_s[16], a_d[16];
#pragma unroll
    for (int t = 0; t < 16; ++t) {
        a_s[t] = af[16 * t + c0];
        a_d[t] = af[256 + 16 * t + c0];
    }
#pragma unroll
    for (int j = 0; j < 4; ++j) {
        int grow = m0 + r0 + j;
        float ssrc = 0.f, sdst = 0.f;
#pragma unroll
        for (int t = 0; t < 16; ++t) {
            float cv = acc[t][j];
            ssrc = fmaf(cv, a_s[t], ssrc);
            sdst = fmaf(cv, a_d[t], sdst);
            int col = 16 * t + c0;
            if (grow < M)
                hpS[(size_t)(col >> 5) * Ns + (size_t)grow * 32 + (col & 31)] = f2bf(cv);
        }
        for (int off = 1; off < 16; off <<= 1) {
            ssrc += __shfl_xor(ssrc, off);
            sdst += __shfl_xor(sdst, off);
        }
        if (c0 == 0 && grow < M) { asrc[grow] = ssrc; adst[grow] = sdst; }
    }
}

// ------------------- aggregation: 8 nodes x 1 slice per wave -------------------
// slice = bid&7 -> XCD-affine (each XCD gathers from ONE 3.2MB slice, L2-hit).
// Lane l owns node (l>>3) of the wave's 8 and cols (l&7)*4 of the slice:
// each 8-lane group serially accumulates ALL edges of its node, so the
// accumulators are per-lane-final -> NO cross-lane reduction epilogue
// (R7 lesson: 400K waves x 25-shfl epilogue dominated at avg degree 16).
// Degree divergence inside a wave handled by w=0 masked iterations.
template<bool OUT_BF16>
__global__ __launch_bounds__(256) void aggregate_kernel(const int* __restrict__ row_ptr,
        const int2* __restrict__ ewc, const unsigned short* __restrict__ hpS,
        void* __restrict__ outp, int n) {
    int bid = blockIdx.x;
    int slice = bid & 7;
    int wid = threadIdx.x >> 6;
    int lane = threadIdx.x & 63;
    int node = (bid >> 3) * 32 + wid * 8 + (lane >> 3);
    int c4 = (lane & 7) * 4;
    bool valid = node < n;
    int nd = valid ? node : 0;
    int beg = row_ptr[nd];
    int end = valid ? row_ptr[nd + 1] : beg;
    const unsigned short* __restrict__ base = hpS + (size_t)slice * ((size_t)n * 32);
    float acc0 = 0.f, acc1 = 0.f, acc2 = 0.f, acc3 = 0.f, rs = 0.f;
    int e = beg;
    while (__any(e < end)) {
        bool act = e < end;
        int idx = act ? e : 0;              // ewc[0] is a valid record
        int2 pw = ewc[idx];
        float w = act ? __int_as_float(pw.y) : 0.f;
        uint2 qu = *(const uint2*)(base + (size_t)(unsigned)pw.x * 32 + c4);
        float f0 = __uint_as_float(qu.x << 16);
        float f1 = __uint_as_float(qu.x & 0xFFFF0000u);
        float f2 = __uint_as_float(qu.y << 16);
        float f3 = __uint_as_float(qu.y & 0xFFFF0000u);
        acc0 = fmaf(w, f0, acc0);
        acc1 = fmaf(w, f1, acc1);
        acc2 = fmaf(w, f2, acc2);
        acc3 = fmaf(w, f3, acc3);
        rs += w;
        ++e;
    }
    if (valid) {
        float inv = 1.f / (rs + EPS_);
        float v0 = acc0 * inv, v1 = acc1 * inv, v2 = acc2 * inv, v3 = acc3 * inv;
        v0 = v0 > 0.f ? v0 : __expf(v0) - 1.f;   // ELU
        v1 = v1 > 0.f ? v1 : __expf(v1) - 1.f;
        v2 = v2 > 0.f ? v2 : __expf(v2) - 1.f;
        v3 = v3 > 0.f ? v3 : __expf(v3) - 1.f;
        size_t o = (size_t)node * 256 + slice * 32 + c4;
        if constexpr (OUT_BF16) {
            ushort4 ov;
            ov.x = f2bf(v0); ov.y = f2bf(v1); ov.z = f2bf(v2); ov.w = f2bf(v3);
            *(ushort4*)((unsigned short*)outp + o) = ov;
        } else {
            float4 ov = {v0, v1, v2, v3};
            *(float4*)((float*)outp + o) = ov;
        }
    }
}

extern "C" void kernel_launch(void* const* d_in, const int* in_sizes, int n_in,
                              void* d_out, int out_size, void* d_ws, size_t ws_size,
                              hipStream_t stream) {
    const float* sr_emb = (const float*)d_in[0];
    const float* tg_emb = (const float*)d_in[1];
    const float* W1 = (const float*)d_in[2];
    const float* a1 = (const float*)d_in[3];
    const float* W2 = (const float*)d_in[4];
    const float* a2 = (const float*)d_in[5];
    const int* adj_sr = (const int*)d_in[6];
    const int* adj_tg = (const int*)d_in[7];
    int N = in_sizes[0] / 256;
    int E = in_sizes[6] / 2;

    char* p = (char*)d_ws;
    auto alloc = [&](size_t bytes) -> void* {
        void* r = (void*)p;
        p += (bytes + 255) & ~(size_t)255;
        return r;
    };
    int nb = (N + 1023) / 1024;
    int* cnt      = (int*)alloc((size_t)N * 4);
    int* row_ptr  = (int*)alloc((size_t)(N + 1) * 4);
    int* cursor   = (int*)alloc((size_t)N * 4);
    int* locpre   = (int*)alloc((size_t)N * 4);
    int* blocksum = (int*)alloc((size_t)nb * 4);
    int* colv     = (int*)alloc((size_t)(E + 16) * 4);
    int* srce     = (int*)alloc((size_t)(E + 16) * 4);
    int2* ewc     = (int2*)alloc((size_t)(E + 16) * 8);
    short* Wt1    = (short*)alloc(256 * 256 * 2);
    short* Wt2    = (short*)alloc(256 * 256 * 2);
    unsigned short* hpS = (unsigned short*)alloc((size_t)N * 256 * 2);  // slice-major
    float* asrc   = (float*)alloc((size_t)N * 4);
    float* adst   = (float*)alloc((size_t)N * 4);
    short* tmp    = (short*)alloc((size_t)N * 256 * 2);

    wt_kernel<<<256, 256, 0, stream>>>(W1, Wt1);
    wt_kernel<<<256, 256, 0, stream>>>(W2, Wt2);

    int gemm_grid = (N + 63) / 64;
    int agg_grid = 8 * ((N + 31) / 32);  // slice = bid&7 (XCD-affine), 32 nodes/block
    int e_grid = (E + 255) / 256;
    int n_grid = (N + 255) / 256;
    (void)n_grid;

    for (int g = 0; g < 2; ++g) {
        const int* srcv = (g == 0 ? adj_sr : adj_tg);
        const int* dstv = srcv + E;
        const float* emb = (g == 0 ? sr_emb : tg_emb);
        float* outg = (float*)d_out + (size_t)g * N * 256;

        hipMemsetAsync(cnt, 0, (size_t)N * 4, stream);
        hist_kernel<<<e_grid, 256, 0, stream>>>(srcv, cnt, E);
        scan1_kernel<<<nb, 256, 0, stream>>>(cnt, locpre, blocksum, N);
        scan2_kernel<<<1, 64, 0, stream>>>(blocksum, nb, row_ptr + N);
        scan3_kernel<<<nb, 256, 0, stream>>>(locpre, blocksum, row_ptr, cursor, N);
        scatter_kernel<<<e_grid, 256, 0, stream>>>(srcv, dstv, cursor, colv, srce, E);

        // layer 1: f32 input -> bf16 tmp (alpha fused into gemm epilogue)
        gemm_kernel<false><<<gemm_grid, 256, 0, stream>>>(emb, Wt1, hpS, a1, asrc, adst, N);
        ew_kernel<<<e_grid, 256, 0, stream>>>(srce, colv, asrc, adst, ewc, E);
        aggregate_kernel<true><<<agg_grid, 256, 0, stream>>>(row_ptr, ewc, hpS, tmp, N);
        // layer 2: bf16 input -> f32 out
        gemm_kernel<true><<<gemm_grid, 256, 0, stream>>>(tmp, Wt2, hpS, a2, asrc, adst, N);
        ew_kernel<<<e_grid, 256, 0, stream>>>(srce, colv, asrc, adst, ewc, E);
        aggregate_kernel<false><<<agg_grid, 256, 0, stream>>>(row_ptr, ewc, hpS, outg, N);
    }
}

// Round 9
// 671.805 us; speedup vs baseline: 1.5613x; 1.2006x over previous
//
#include <hip/hip_runtime.h>

#define NEG_SLOPE 0.2f
#define EPS_ 1e-9f

typedef __attribute__((ext_vector_type(8))) short short8v;
typedef __attribute__((ext_vector_type(4))) float f32x4;

__device__ __forceinline__ float bf2f(unsigned short u) {
    return __uint_as_float(((unsigned)u) << 16);
}
__device__ __forceinline__ unsigned short f2bf(float f) {
    unsigned u = __float_as_uint(f);
    u = u + 0x7FFFu + ((u >> 16) & 1u);   // round-to-nearest-even
    return (unsigned short)(u >> 16);
}

// ------------------- CSR build (exact, no padding) -------------------
__global__ void hist_kernel(const int* __restrict__ src, int* __restrict__ cnt, int E) {
    int i = blockIdx.x * blockDim.x + threadIdx.x;
    if (i < E) atomicAdd(&cnt[src[i]], 1);
}

__global__ __launch_bounds__(256) void scan1_kernel(const int* __restrict__ cnt,
        int* __restrict__ locpre, int* __restrict__ blocksum, int n) {
    int t = threadIdx.x;
    int lane = t & 63, wid = t >> 6;
    int base = blockIdx.x * 1024 + t * 4;
    int4 v = {0, 0, 0, 0};
    if (base + 3 < n) {
        v = *(const int4*)(cnt + base);
    } else {
        if (base + 0 < n) v.x = cnt[base + 0];
        if (base + 1 < n) v.y = cnt[base + 1];
        if (base + 2 < n) v.z = cnt[base + 2];
        if (base + 3 < n) v.w = cnt[base + 3];
    }
    int s = v.x + v.y + v.z + v.w;
    int incl = s;
    for (int off = 1; off < 64; off <<= 1) {
        int u = __shfl_up(incl, off);
        if (lane >= off) incl += u;
    }
    __shared__ int ws[4];
    if (lane == 63) ws[wid] = incl;
    __syncthreads();
    int woff = 0;
    for (int i = 0; i < wid; ++i) woff += ws[i];
    int excl = incl - s + woff;
    int4 o;
    o.x = excl; o.y = excl + v.x; o.z = o.y + v.y; o.w = o.z + v.z;
    if (base + 3 < n) {
        *(int4*)(locpre + base) = o;
    } else {
        if (base + 0 < n) locpre[base + 0] = o.x;
        if (base + 1 < n) locpre[base + 1] = o.y;
        if (base + 2 < n) locpre[base + 2] = o.z;
        if (base + 3 < n) locpre[base + 3] = o.w;
    }
    if (t == 255) blocksum[blockIdx.x] = excl + s;
}

// scan of block sums; also writes grand total (=E) to *totout (= row_ptr[n])
__global__ __launch_bounds__(64) void scan2_kernel(int* __restrict__ blocksum, int nb,
        int* __restrict__ totout) {
    int lane = threadIdx.x;
    int carry = 0;
    for (int base = 0; base < nb; base += 64) {
        int v = (base + lane < nb) ? blocksum[base + lane] : 0;
        int incl = v;
        for (int off = 1; off < 64; off <<= 1) {
            int u = __shfl_up(incl, off);
            if (lane >= off) incl += u;
        }
        int tot = __shfl(incl, 63);
        if (base + lane < nb) blocksum[base + lane] = incl - v + carry;
        carry += tot;
    }
    if (lane == 0) *totout = carry;
}

__global__ __launch_bounds__(256) void scan3_kernel(const int* __restrict__ locpre,
        const int* __restrict__ blocksum, int* __restrict__ row_ptr,
        int* __restrict__ cursor, int n) {
    int base = blockIdx.x * 1024 + threadIdx.x * 4;
    int off = blocksum[blockIdx.x];
    if (base + 3 < n) {
        int4 v = *(const int4*)(locpre + base);
        v.x += off; v.y += off; v.z += off; v.w += off;
        *(int4*)(row_ptr + base) = v;
        *(int4*)(cursor + base) = v;
    } else {
        for (int i = 0; i < 4; ++i) {
            if (base + i < n) {
                int v = locpre[base + i] + off;
                row_ptr[base + i] = v;
                cursor[base + i] = v;
            }
        }
    }
}

__global__ void scatter_kernel(const int* __restrict__ src, const int* __restrict__ dst,
        int* __restrict__ cursor, int* __restrict__ colv, int* __restrict__ srce, int E) {
    int i = blockIdx.x * blockDim.x + threadIdx.x;
    if (i < E) {
        int s = src[i];
        int p = atomicAdd(&cursor[s], 1);
        colv[p] = dst[i];
        srce[p] = s;
    }
}

// ------------------- edge records {col, w}, CSR order, exact range -------------
__global__ __launch_bounds__(256) void ew_kernel(const int* __restrict__ srce,
        const int* __restrict__ colv, const float* __restrict__ asrc,
        const float* __restrict__ adst, int2* __restrict__ ewc, int E) {
    int i = blockIdx.x * blockDim.x + threadIdx.x;
    if (i < E) {
        int d = colv[i];
        float x = asrc[srce[i]] + adst[d];
        float lr = fmaxf(x, NEG_SLOPE * x);   // leaky_relu
        ewc[i] = make_int2(d, __float_as_int(__expf(-lr)));
    }
}

// ------------------- W transpose + bf16 convert -------------------
__global__ void wt_kernel(const float* __restrict__ W, short* __restrict__ Wt) {
    int nn = blockIdx.x, k = threadIdx.x;
    Wt[nn * 256 + k] = (short)f2bf(W[k * 256 + nn]);   // Wt[n][k] = W[k][n]
}

// ------------------- GEMM: h' = h @ W (bf16 MFMA) + fused alpha dot-products ----
// h' written SLICE-MAJOR: hpS[slice][node][32] (slice = col>>5) for the
// XCD-affine aggregate (each slice = 3.2MB, fits one XCD's 4MB L2).
template<bool IN_BF16>
__global__ __launch_bounds__(256) void gemm_kernel(const void* __restrict__ hin,
        const short* __restrict__ Wt, unsigned short* __restrict__ hpS,
        const float* __restrict__ af, float* __restrict__ asrc,
        float* __restrict__ adst, int M) {
    __shared__ short As[64 * 40];    // 64 rows x 32 k, pad to 40
    __shared__ short Bt[256 * 40];   // 256 n-rows x 32 k, pad to 40
    int tid = threadIdx.x;
    int lane = tid & 63, w = tid >> 6;
    int m0 = blockIdx.x * 64;
    size_t Ns = (size_t)M * 32;      // slice stride

    f32x4 acc[16];
#pragma unroll
    for (int t = 0; t < 16; ++t) acc[t] = (f32x4){0.f, 0.f, 0.f, 0.f};

    int ar = tid >> 2;          // 0..63
    int ac = (tid & 3) * 8;     // 0,8,16,24
    int agrow = m0 + ar;

    for (int kk = 0; kk < 256; kk += 32) {
        short8v av = (short8v){0,0,0,0,0,0,0,0};
        if constexpr (IN_BF16) {
            if (agrow < M)
                av = *(const short8v*)((const short*)hin + (size_t)agrow * 256 + kk + ac);
        } else {
            if (agrow < M) {
                const float* s = (const float*)hin + (size_t)agrow * 256 + kk + ac;
                float4 v0 = *(const float4*)s;
                float4 v1 = *(const float4*)(s + 4);
                av[0] = (short)f2bf(v0.x); av[1] = (short)f2bf(v0.y);
                av[2] = (short)f2bf(v0.z); av[3] = (short)f2bf(v0.w);
                av[4] = (short)f2bf(v1.x); av[5] = (short)f2bf(v1.y);
                av[6] = (short)f2bf(v1.z); av[7] = (short)f2bf(v1.w);
            }
        }
        *(short8v*)&As[ar * 40 + ac] = av;
        {
            const short* s = Wt + (size_t)tid * 256 + kk;
#pragma unroll
            for (int i = 0; i < 4; ++i)
                *(short8v*)&Bt[tid * 40 + i * 8] = *(const short8v*)(s + i * 8);
        }
        __syncthreads();
        short8v a = *(const short8v*)&As[(16 * w + (lane & 15)) * 40 + (lane >> 4) * 8];
#pragma unroll
        for (int t = 0; t < 16; ++t) {
            short8v b = *(const short8v*)&Bt[(16 * t + (lane & 15)) * 40 + (lane >> 4) * 8];
            acc[t] = __builtin_amdgcn_mfma_f32_16x16x32_bf16(a, b, acc[t], 0, 0, 0);
        }
        __syncthreads();
    }
    int r0 = 16 * w + (lane >> 4) * 4;
    int c0 = lane & 15;
    float a_s[16], a_d[16];
#pragma unroll
    for (int t = 0; t < 16; ++t) {
        a_s[t] = af[16 * t + c0];
        a_d[t] = af[256 + 16 * t + c0];
    }
#pragma unroll
    for (int j = 0; j < 4; ++j) {
        int grow = m0 + r0 + j;
        float ssrc = 0.f, sdst = 0.f;
#pragma unroll
        for (int t = 0; t < 16; ++t) {
            float cv = acc[t][j];
            ssrc = fmaf(cv, a_s[t], ssrc);
            sdst = fmaf(cv, a_d[t], sdst);
            int col = 16 * t + c0;
            if (grow < M)
                hpS[(size_t)(col >> 5) * Ns + (size_t)grow * 32 + (col & 31)] = f2bf(cv);
        }
        for (int off = 1; off < 16; off <<= 1) {
            ssrc += __shfl_xor(ssrc, off);
            sdst += __shfl_xor(sdst, off);
        }
        if (c0 == 0 && grow < M) { asrc[grow] = ssrc; adst[grow] = sdst; }
    }
}

// ------------------- aggregation: 8 nodes x 1 slice per wave, 8-deep pipeline ---
// slice = bid&7 -> XCD-affine (each XCD gathers from ONE 3.2MB slice, L2-hit).
// Lane l owns node (l>>3) and cols (l&7)*4 -> per-lane-final accumulators, no
// shfl epilogue (R7 lesson). Edge walk batched 8-at-a-time: 8 independent ewc
// loads issue, then 8 gathers -> 2 memory epochs per 8 edges instead of 16
// (R8 lesson: VGPR=12 dependent chain was latency-serialized at 113us).
// Tail: indices clamped to end-1 (valid records), weights zeroed for k>=m.
#define EWLD(pp, kk) int2 pp = ewc[min(e + kk, last)];
#define GA(qq, pp)   uint2 qq = *(const uint2*)(base + (size_t)(unsigned)pp.x * 32 + c4);
#define WSEL(ww, pp, kk) float ww = (kk < m) ? __int_as_float(pp.y) : 0.f;
#define ACC(qq, ww) { \
    acc0 = fmaf(ww, __uint_as_float(qq.x << 16), acc0); \
    acc1 = fmaf(ww, __uint_as_float(qq.x & 0xFFFF0000u), acc1); \
    acc2 = fmaf(ww, __uint_as_float(qq.y << 16), acc2); \
    acc3 = fmaf(ww, __uint_as_float(qq.y & 0xFFFF0000u), acc3); \
    rs += ww; }

template<bool OUT_BF16>
__global__ __launch_bounds__(256) void aggregate_kernel(const int* __restrict__ row_ptr,
        const int2* __restrict__ ewc, const unsigned short* __restrict__ hpS,
        void* __restrict__ outp, int n) {
    int bid = blockIdx.x;
    int slice = bid & 7;
    int wid = threadIdx.x >> 6;
    int lane = threadIdx.x & 63;
    int node = (bid >> 3) * 32 + wid * 8 + (lane >> 3);
    int c4 = (lane & 7) * 4;
    bool valid = node < n;
    int nd = valid ? node : 0;
    int beg = row_ptr[nd];
    int end = valid ? row_ptr[nd + 1] : beg;
    int last = end - 1;
    const unsigned short* __restrict__ base = hpS + (size_t)slice * ((size_t)n * 32);
    float acc0 = 0.f, acc1 = 0.f, acc2 = 0.f, acc3 = 0.f, rs = 0.f;
    for (int e = beg; e < end; e += 8) {
        int m = end - e;                       // per-lane (uniform in 8-lane group)
        EWLD(p0, 0) EWLD(p1, 1) EWLD(p2, 2) EWLD(p3, 3)
        EWLD(p4, 4) EWLD(p5, 5) EWLD(p6, 6) EWLD(p7, 7)
        GA(q0, p0) GA(q1, p1) GA(q2, p2) GA(q3, p3)
        GA(q4, p4) GA(q5, p5) GA(q6, p6) GA(q7, p7)
        WSEL(w0, p0, 0) WSEL(w1, p1, 1) WSEL(w2, p2, 2) WSEL(w3, p3, 3)
        WSEL(w4, p4, 4) WSEL(w5, p5, 5) WSEL(w6, p6, 6) WSEL(w7, p7, 7)
        ACC(q0, w0) ACC(q1, w1) ACC(q2, w2) ACC(q3, w3)
        ACC(q4, w4) ACC(q5, w5) ACC(q6, w6) ACC(q7, w7)
    }
    if (valid) {
        float inv = 1.f / (rs + EPS_);
        float v0 = acc0 * inv, v1 = acc1 * inv, v2 = acc2 * inv, v3 = acc3 * inv;
        v0 = v0 > 0.f ? v0 : __expf(v0) - 1.f;   // ELU
        v1 = v1 > 0.f ? v1 : __expf(v1) - 1.f;
        v2 = v2 > 0.f ? v2 : __expf(v2) - 1.f;
        v3 = v3 > 0.f ? v3 : __expf(v3) - 1.f;
        size_t o = (size_t)node * 256 + slice * 32 + c4;
        if constexpr (OUT_BF16) {
            ushort4 ov;
            ov.x = f2bf(v0); ov.y = f2bf(v1); ov.z = f2bf(v2); ov.w = f2bf(v3);
            *(ushort4*)((unsigned short*)outp + o) = ov;
        } else {
            float4 ov = {v0, v1, v2, v3};
            *(float4*)((float*)outp + o) = ov;
        }
    }
}

extern "C" void kernel_launch(void* const* d_in, const int* in_sizes, int n_in,
                              void* d_out, int out_size, void* d_ws, size_t ws_size,
                              hipStream_t stream) {
    const float* sr_emb = (const float*)d_in[0];
    const float* tg_emb = (const float*)d_in[1];
    const float* W1 = (const float*)d_in[2];
    const float* a1 = (const float*)d_in[3];
    const float* W2 = (const float*)d_in[4];
    const float* a2 = (const float*)d_in[5];
    const int* adj_sr = (const int*)d_in[6];
    const int* adj_tg = (const int*)d_in[7];
    int N = in_sizes[0] / 256;
    int E = in_sizes[6] / 2;

    char* p = (char*)d_ws;
    auto alloc = [&](size_t bytes) -> void* {
        void* r = (void*)p;
        p += (bytes + 255) & ~(size_t)255;
        return r;
    };
    int nb = (N + 1023) / 1024;
    int* cnt      = (int*)alloc((size_t)N * 4);
    int* row_ptr  = (int*)alloc((size_t)(N + 1) * 4);
    int* cursor   = (int*)alloc((size_t)N * 4);
    int* locpre   = (int*)alloc((size_t)N * 4);
    int* blocksum = (int*)alloc((size_t)nb * 4);
    int* colv     = (int*)alloc((size_t)(E + 16) * 4);
    int* srce     = (int*)alloc((size_t)(E + 16) * 4);
    int2* ewc     = (int2*)alloc((size_t)(E + 16) * 8);
    short* Wt1    = (short*)alloc(256 * 256 * 2);
    short* Wt2    = (short*)alloc(256 * 256 * 2);
    unsigned short* hpS = (unsigned short*)alloc((size_t)N * 256 * 2);  // slice-major
    float* asrc   = (float*)alloc((size_t)N * 4);
    float* adst   = (float*)alloc((size_t)N * 4);
    short* tmp    = (short*)alloc((size_t)N * 256 * 2);

    wt_kernel<<<256, 256, 0, stream>>>(W1, Wt1);
    wt_kernel<<<256, 256, 0, stream>>>(W2, Wt2);

    int gemm_grid = (N + 63) / 64;
    int agg_grid = 8 * ((N + 31) / 32);  // slice = bid&7 (XCD-affine), 32 nodes/block
    int e_grid = (E + 255) / 256;

    for (int g = 0; g < 2; ++g) {
        const int* srcv = (g == 0 ? adj_sr : adj_tg);
        const int* dstv = srcv + E;
        const float* emb = (g == 0 ? sr_emb : tg_emb);
        float* outg = (float*)d_out + (size_t)g * N * 256;

        hipMemsetAsync(cnt, 0, (size_t)N * 4, stream);
        hist_kernel<<<e_grid, 256, 0, stream>>>(srcv, cnt, E);
        scan1_kernel<<<nb, 256, 0, stream>>>(cnt, locpre, blocksum, N);
        scan2_kernel<<<1, 64, 0, stream>>>(blocksum, nb, row_ptr + N);
        scan3_kernel<<<nb, 256, 0, stream>>>(locpre, blocksum, row_ptr, cursor, N);
        scatter_kernel<<<e_grid, 256, 0, stream>>>(srcv, dstv, cursor, colv, srce, E);

        // layer 1: f32 input -> bf16 tmp (alpha fused into gemm epilogue)
        gemm_kernel<false><<<gemm_grid, 256, 0, stream>>>(emb, Wt1, hpS, a1, asrc, adst, N);
        ew_kernel<<<e_grid, 256, 0, stream>>>(srce, colv, asrc, adst, ewc, E);
        aggregate_kernel<true><<<agg_grid, 256, 0, stream>>>(row_ptr, ewc, hpS, tmp, N);
        // layer 2: bf16 input -> f32 out
        gemm_kernel<true><<<gemm_grid, 256, 0, stream>>>(tmp, Wt2, hpS, a2, asrc, adst, N);
        ew_kernel<<<e_grid, 256, 0, stream>>>(srce, colv, asrc, adst, ewc, E);
        aggregate_kernel<false><<<agg_grid, 256, 0, stream>>>(row_ptr, ewc, hpS, outg, N);
    }
}

// Round 10
// 636.102 us; speedup vs baseline: 1.6489x; 1.0561x over previous
//
#include <hip/hip_runtime.h>

#define NEG_SLOPE 0.2f
#define EPS_ 1e-9f

typedef __attribute__((ext_vector_type(8))) short short8v;
typedef __attribute__((ext_vector_type(4))) float f32x4;

__device__ __forceinline__ float bf2f(unsigned short u) {
    return __uint_as_float(((unsigned)u) << 16);
}
__device__ __forceinline__ unsigned short f2bf(float f) {
    unsigned u = __float_as_uint(f);
    u = u + 0x7FFFu + ((u >> 16) & 1u);   // round-to-nearest-even
    return (unsigned short)(u >> 16);
}

// ==================== CSR build (both graphs via blockIdx.y) ====================
__global__ void hist_kernel(const int* __restrict__ srcA, const int* __restrict__ srcB,
        int* __restrict__ cnt, int E, int n) {
    int g = blockIdx.y;
    const int* src = g ? srcB : srcA;
    int* c = cnt + (size_t)g * n;
    int i = blockIdx.x * blockDim.x + threadIdx.x;
    if (i < E) atomicAdd(&c[src[i]], 1);
}

__global__ __launch_bounds__(256) void scan1_kernel(const int* __restrict__ cnt,
        int* __restrict__ locpre, int* __restrict__ blocksum, int n, int nb) {
    int g = blockIdx.y;
    const int* cg = cnt + (size_t)g * n;
    int* lg = locpre + (size_t)g * n;
    int* bs = blocksum + (size_t)g * nb;
    int t = threadIdx.x;
    int lane = t & 63, wid = t >> 6;
    int base = blockIdx.x * 1024 + t * 4;
    int4 v = {0, 0, 0, 0};
    if (base + 3 < n) {
        v = *(const int4*)(cg + base);
    } else {
        if (base + 0 < n) v.x = cg[base + 0];
        if (base + 1 < n) v.y = cg[base + 1];
        if (base + 2 < n) v.z = cg[base + 2];
        if (base + 3 < n) v.w = cg[base + 3];
    }
    int s = v.x + v.y + v.z + v.w;
    int incl = s;
    for (int off = 1; off < 64; off <<= 1) {
        int u = __shfl_up(incl, off);
        if (lane >= off) incl += u;
    }
    __shared__ int ws[4];
    if (lane == 63) ws[wid] = incl;
    __syncthreads();
    int woff = 0;
    for (int i = 0; i < wid; ++i) woff += ws[i];
    int excl = incl - s + woff;
    int4 o;
    o.x = excl; o.y = excl + v.x; o.z = o.y + v.y; o.w = o.z + v.z;
    if (base + 3 < n) {
        *(int4*)(lg + base) = o;
    } else {
        if (base + 0 < n) lg[base + 0] = o.x;
        if (base + 1 < n) lg[base + 1] = o.y;
        if (base + 2 < n) lg[base + 2] = o.z;
        if (base + 3 < n) lg[base + 3] = o.w;
    }
    if (t == 255) bs[blockIdx.x] = excl + s;
}

__global__ __launch_bounds__(64) void scan2_kernel(int* __restrict__ blocksum, int nb,
        int* __restrict__ row_ptr, int n) {
    int g = blockIdx.y;
    int* bs = blocksum + (size_t)g * nb;
    int lane = threadIdx.x;
    int carry = 0;
    for (int base = 0; base < nb; base += 64) {
        int v = (base + lane < nb) ? bs[base + lane] : 0;
        int incl = v;
        for (int off = 1; off < 64; off <<= 1) {
            int u = __shfl_up(incl, off);
            if (lane >= off) incl += u;
        }
        int tot = __shfl(incl, 63);
        if (base + lane < nb) bs[base + lane] = incl - v + carry;
        carry += tot;
    }
    if (lane == 0) row_ptr[(size_t)g * (n + 1) + n] = carry;   // == E
}

__global__ __launch_bounds__(256) void scan3_kernel(const int* __restrict__ locpre,
        const int* __restrict__ blocksum, int* __restrict__ row_ptr,
        int* __restrict__ cursor, int n, int nb) {
    int g = blockIdx.y;
    const int* lg = locpre + (size_t)g * n;
    const int* bs = blocksum + (size_t)g * nb;
    int* rp = row_ptr + (size_t)g * (n + 1);
    int* cu = cursor + (size_t)g * n;
    int base = blockIdx.x * 1024 + threadIdx.x * 4;
    int off = bs[blockIdx.x];
    if (base + 3 < n) {
        int4 v = *(const int4*)(lg + base);
        v.x += off; v.y += off; v.z += off; v.w += off;
        *(int4*)(rp + base) = v;
        *(int4*)(cu + base) = v;
    } else {
        for (int i = 0; i < 4; ++i) {
            if (base + i < n) {
                int v = lg[base + i] + off;
                rp[base + i] = v;
                cu[base + i] = v;
            }
        }
    }
}

__global__ void scatter_kernel(const int* __restrict__ srcA, const int* __restrict__ dstA,
        const int* __restrict__ srcB, const int* __restrict__ dstB,
        int* __restrict__ cursor, int* __restrict__ colv, int E, int n, int ecap) {
    int g = blockIdx.y;
    const int* src = g ? srcB : srcA;
    const int* dst = g ? dstB : dstA;
    int* cu = cursor + (size_t)g * n;
    int* cv = colv + (size_t)g * ecap;
    int i = blockIdx.x * blockDim.x + threadIdx.x;
    if (i < E) {
        int p = atomicAdd(&cu[src[i]], 1);
        cv[p] = dst[i];
    }
}

// ==================== W transpose + bf16 convert ====================
__global__ void wt_kernel(const float* __restrict__ W, short* __restrict__ Wt) {
    int nn = blockIdx.x, k = threadIdx.x;
    Wt[nn * 256 + k] = (short)f2bf(W[k * 256 + nn]);   // Wt[n][k] = W[k][n]
}

// ==================== GEMM: h' = h @ W, B-half resident in LDS ====================
// grid (rowtiles, 2 colhalves, 2 graphs), 512 thr = 8 waves.
// LDS = exactly 64KB: Bt[kc][n][8] (kc = k>>3, n in [0,128)) -> ds_read_b128
// B-frags 2-way max (free). A loaded global->reg in MFMA fragment layout; the
// only barrier is after the one-time B load (R2-R9 gemm restaged B 8x/block).
__global__ __launch_bounds__(512) void gemm_kernel(const float* __restrict__ hinA,
        const float* __restrict__ hinB, const short* __restrict__ Wt,
        unsigned short* __restrict__ hpS_all, int M) {
    __shared__ short Bt[32768];   // 64 KB exact
    int tid = threadIdx.x;
    int lane = tid & 63, w = tid >> 6;
    int ch = blockIdx.y;
    int g = blockIdx.z;
    const float* hin = g ? hinB : hinA;
    unsigned short* hpS = hpS_all + (size_t)g * M * 256;

    // ---- load B half (128 cols x 256 k) into LDS ----
    {
        int n = tid >> 2;
        int kb = (tid & 3) * 64;
        const short* srcw = Wt + (size_t)(ch * 128 + n) * 256;
#pragma unroll
        for (int i = 0; i < 8; ++i) {
            int k = kb + i * 8;
            short8v v = *(const short8v*)(srcw + k);
            *(short8v*)&Bt[((k >> 3) * 128 + n) * 8] = v;
        }
    }
    __syncthreads();

    int row0 = (blockIdx.x * 8 + w) * 16;
    if (row0 >= M) return;                 // M % 16 == 0, so full tiles only

    // ---- A fragments: row = lane&15, k = c*32 + (lane>>4)*8 ----
    const float* Ap = hin + (size_t)(row0 + (lane & 15)) * 256 + (lane >> 4) * 8;
    short8v af[8];
#pragma unroll
    for (int half = 0; half < 2; ++half) {
        float4 u0[4], u1[4];
#pragma unroll
        for (int c = 0; c < 4; ++c) {
            u0[c] = *(const float4*)(Ap + (half * 4 + c) * 32);
            u1[c] = *(const float4*)(Ap + (half * 4 + c) * 32 + 4);
        }
#pragma unroll
        for (int c = 0; c < 4; ++c) {
            short8v a;
            a[0] = (short)f2bf(u0[c].x); a[1] = (short)f2bf(u0[c].y);
            a[2] = (short)f2bf(u0[c].z); a[3] = (short)f2bf(u0[c].w);
            a[4] = (short)f2bf(u1[c].x); a[5] = (short)f2bf(u1[c].y);
            a[6] = (short)f2bf(u1[c].z); a[7] = (short)f2bf(u1[c].w);
            af[half * 4 + c] = a;
        }
    }

    f32x4 acc[8];
#pragma unroll
    for (int t = 0; t < 8; ++t) acc[t] = (f32x4){0.f, 0.f, 0.f, 0.f};

#pragma unroll
    for (int c = 0; c < 8; ++c) {
        int kcf = c * 4 + (lane >> 4);
#pragma unroll
        for (int t = 0; t < 8; ++t) {
            short8v b = *(const short8v*)&Bt[(kcf * 128 + t * 16 + (lane & 15)) * 8];
            acc[t] = __builtin_amdgcn_mfma_f32_16x16x32_bf16(af[c], b, acc[t], 0, 0, 0);
        }
    }

    // ---- epilogue: slice-major store hpS[col>>5][row][col&31] ----
    size_t Ns = (size_t)M * 32;
#pragma unroll
    for (int t = 0; t < 8; ++t) {
        int col = ch * 128 + t * 16 + (lane & 15);
        unsigned short* dst = hpS + (size_t)(col >> 5) * Ns + (col & 31);
#pragma unroll
        for (int j = 0; j < 4; ++j) {
            int row = row0 + (lane >> 4) * 4 + j;
            dst[(size_t)row * 32] = f2bf(acc[t][j]);
        }
    }
}

// ==================== alpha: asrc/adst dots from hpS (both graphs) ====================
__global__ __launch_bounds__(256) void alpha_kernel(const unsigned short* __restrict__ hpS,
        const float* __restrict__ a, float* __restrict__ asrc, float* __restrict__ adst,
        int n) {
    int gid = (blockIdx.x * 256 + threadIdx.x) >> 3;   // node id across 2N
    int ln8 = threadIdx.x & 7;
    if (gid >= 2 * n) return;
    int g = gid >= n;
    int node = gid - g * n;
    const unsigned short* base = hpS + (size_t)g * n * 256;
    float s0 = 0.f, s1 = 0.f;
#pragma unroll
    for (int s = 0; s < 8; ++s) {
        uint2 q = *(const uint2*)(base + (size_t)s * ((size_t)n * 32)
                                  + (size_t)node * 32 + ln8 * 4);
        float f0 = __uint_as_float(q.x << 16);
        float f1 = __uint_as_float(q.x & 0xFFFF0000u);
        float f2 = __uint_as_float(q.y << 16);
        float f3 = __uint_as_float(q.y & 0xFFFF0000u);
        int ax = s * 32 + ln8 * 4;
        s0 += f0 * a[ax] + f1 * a[ax + 1] + f2 * a[ax + 2] + f3 * a[ax + 3];
        s1 += f0 * a[256 + ax] + f1 * a[257 + ax] + f2 * a[258 + ax] + f3 * a[259 + ax];
    }
    for (int off = 1; off < 8; off <<= 1) {
        s0 += __shfl_xor(s0, off);
        s1 += __shfl_xor(s1, off);
    }
    if (ln8 == 0) { asrc[gid] = s0; adst[gid] = s1; }
}

// ==================== aggregation: 8 nodes x 1 slice per wave, inline weights ===
// slice = blockIdx.x&7 (XCD-affine; hpS slice 3.2MB + adst 200KB L2-resident).
// Weight computed inline: w = exp(-lrelu(asrc[node] + adst[j])) -- removes the
// 8x-replicated 8B ewc stream (R9: 51MB of 70MB fetch) and the ew kernels.
// 8-deep batch: colv loads, then adst+hp gathers in parallel epochs.
__global__ __launch_bounds__(256) void aggregate_kernel(const int* __restrict__ row_ptr,
        const int* __restrict__ colv, const float* __restrict__ asrc,
        const float* __restrict__ adst, const unsigned short* __restrict__ hpS,
        float* __restrict__ outp, int n, int ecap) {
    int slice = blockIdx.x & 7;
    int ngrp = blockIdx.x >> 3;
    int g = blockIdx.y;
    int wid = threadIdx.x >> 6, lane = threadIdx.x & 63;
    int node = ngrp * 32 + wid * 8 + (lane >> 3);
    int c4 = (lane & 7) * 4;
    bool valid = node < n;
    int nd = valid ? node : 0;
    const int* rp = row_ptr + (size_t)g * (n + 1);
    int beg = rp[nd];
    int end = valid ? rp[nd + 1] : beg;
    int last = end - 1;
    const int* cv = colv + (size_t)g * ecap;
    const float* ad = adst + (size_t)g * n;
    float ai = asrc[(size_t)g * n + nd];
    const unsigned short* base = hpS + (size_t)g * n * 256 + (size_t)slice * ((size_t)n * 32);

    float acc0 = 0.f, acc1 = 0.f, acc2 = 0.f, acc3 = 0.f, rs = 0.f;
#define JLD(jj, kk) int jj = cv[min(e + kk, last)];
#define DGA(dd, jj) float dd = ad[jj];
#define HGA(qq, jj) uint2 qq = *(const uint2*)(base + (size_t)(unsigned)jj * 32 + c4);
#define WCMP(ww, dd, kk) float ww; { float x_ = ai + dd; \
    ww = (kk < m) ? __expf(-fmaxf(x_, NEG_SLOPE * x_)) : 0.f; }
#define ACC(qq, ww) { \
    acc0 = fmaf(ww, __uint_as_float(qq.x << 16), acc0); \
    acc1 = fmaf(ww, __uint_as_float(qq.x & 0xFFFF0000u), acc1); \
    acc2 = fmaf(ww, __uint_as_float(qq.y << 16), acc2); \
    acc3 = fmaf(ww, __uint_as_float(qq.y & 0xFFFF0000u), acc3); \
    rs += ww; }

    for (int e = beg; e < end; e += 8) {
        int m = end - e;
        JLD(j0, 0) JLD(j1, 1) JLD(j2, 2) JLD(j3, 3)
        JLD(j4, 4) JLD(j5, 5) JLD(j6, 6) JLD(j7, 7)
        DGA(d0, j0) DGA(d1, j1) DGA(d2, j2) DGA(d3, j3)
        DGA(d4, j4) DGA(d5, j5) DGA(d6, j6) DGA(d7, j7)
        HGA(q0, j0) HGA(q1, j1) HGA(q2, j2) HGA(q3, j3)
        HGA(q4, j4) HGA(q5, j5) HGA(q6, j6) HGA(q7, j7)
        WCMP(w0, d0, 0) WCMP(w1, d1, 1) WCMP(w2, d2, 2) WCMP(w3, d3, 3)
        WCMP(w4, d4, 4) WCMP(w5, d5, 5) WCMP(w6, d6, 6) WCMP(w7, d7, 7)
        ACC(q0, w0) ACC(q1, w1) ACC(q2, w2) ACC(q3, w3)
        ACC(q4, w4) ACC(q5, w5) ACC(q6, w6) ACC(q7, w7)
    }
    if (valid) {
        float inv = 1.f / (rs + EPS_);
        float v0 = acc0 * inv, v1 = acc1 * inv, v2 = acc2 * inv, v3 = acc3 * inv;
        v0 = v0 > 0.f ? v0 : __expf(v0) - 1.f;   // ELU
        v1 = v1 > 0.f ? v1 : __expf(v1) - 1.f;
        v2 = v2 > 0.f ? v2 : __expf(v2) - 1.f;
        v3 = v3 > 0.f ? v3 : __expf(v3) - 1.f;
        float4 ov = {v0, v1, v2, v3};
        *(float4*)(outp + (size_t)g * n * 256 + (size_t)node * 256 + slice * 32 + c4) = ov;
    }
}

extern "C" void kernel_launch(void* const* d_in, const int* in_sizes, int n_in,
                              void* d_out, int out_size, void* d_ws, size_t ws_size,
                              hipStream_t stream) {
    const float* sr_emb = (const float*)d_in[0];
    const float* tg_emb = (const float*)d_in[1];
    const float* W1 = (const float*)d_in[2];
    const float* a1 = (const float*)d_in[3];
    const float* W2 = (const float*)d_in[4];
    const float* a2 = (const float*)d_in[5];
    const int* adj_sr = (const int*)d_in[6];
    const int* adj_tg = (const int*)d_in[7];
    int N = in_sizes[0] / 256;
    int E = in_sizes[6] / 2;

    char* p = (char*)d_ws;
    auto alloc = [&](size_t bytes) -> void* {
        void* r = (void*)p;
        p += (bytes + 255) & ~(size_t)255;
        return r;
    };
    int nb = (N + 1023) / 1024;
    int ecap = E + 8;
    int* cnt      = (int*)alloc((size_t)2 * N * 4);
    int* row_ptr  = (int*)alloc((size_t)2 * (N + 1) * 4);
    int* cursor   = (int*)alloc((size_t)2 * N * 4);
    int* locpre   = (int*)alloc((size_t)2 * N * 4);
    int* blocksum = (int*)alloc((size_t)2 * nb * 4);
    int* colv     = (int*)alloc((size_t)2 * ecap * 4);
    short* Wt1    = (short*)alloc(256 * 256 * 2);
    short* Wt2    = (short*)alloc(256 * 256 * 2);
    unsigned short* hpS = (unsigned short*)alloc((size_t)2 * N * 256 * 2); // [g][8][N][32]
    float* asrc   = (float*)alloc((size_t)2 * N * 4);
    float* adst   = (float*)alloc((size_t)2 * N * 4);
    float* outf   = (float*)d_out;   // layer-1 tmp (f32) AND final output

    // ---- CSR build, both graphs ----
    hipMemsetAsync(cnt, 0, (size_t)2 * N * 4, stream);
    wt_kernel<<<256, 256, 0, stream>>>(W1, Wt1);
    wt_kernel<<<256, 256, 0, stream>>>(W2, Wt2);
    int e_grid = (E + 255) / 256;
    hist_kernel<<<dim3(e_grid, 2), 256, 0, stream>>>(adj_sr, adj_tg, cnt, E, N);
    scan1_kernel<<<dim3(nb, 2), 256, 0, stream>>>(cnt, locpre, blocksum, N, nb);
    scan2_kernel<<<dim3(1, 2), 64, 0, stream>>>(blocksum, nb, row_ptr, N);
    scan3_kernel<<<dim3(nb, 2), 256, 0, stream>>>(locpre, blocksum, row_ptr, cursor, N, nb);
    scatter_kernel<<<dim3(e_grid, 2), 256, 0, stream>>>(adj_sr, adj_sr + E,
            adj_tg, adj_tg + E, cursor, colv, E, N, ecap);

    int gemm_rt = (N + 127) / 128;
    int alpha_grid = (2 * N + 31) / 32;
    int agg_gx = 8 * ((N + 31) / 32);

    // ---- layer 1: emb(f32) -> hpS -> alpha -> aggregate -> d_out (f32 tmp) ----
    gemm_kernel<<<dim3(gemm_rt, 2, 2), 512, 0, stream>>>(sr_emb, tg_emb, Wt1, hpS, N);
    alpha_kernel<<<alpha_grid, 256, 0, stream>>>(hpS, a1, asrc, adst, N);
    aggregate_kernel<<<dim3(agg_gx, 2), 256, 0, stream>>>(row_ptr, colv, asrc, adst,
            hpS, outf, N, ecap);
    // ---- layer 2: d_out(f32) -> hpS -> alpha -> aggregate -> d_out (final) ----
    gemm_kernel<<<dim3(gemm_rt, 2, 2), 512, 0, stream>>>(outf, outf + (size_t)N * 256,
            Wt2, hpS, N);
    alpha_kernel<<<alpha_grid, 256, 0, stream>>>(hpS, a2, asrc, adst, N);
    aggregate_kernel<<<dim3(agg_gx, 2), 256, 0, stream>>>(row_ptr, colv, asrc, adst,
            hpS, outf, N, ecap);
}